// Round 11
// baseline (85495.105 us; speedup 1.0000x reference)
//
#include <hip/hip_runtime.h>
#include <cstdint>
#include <cstddef>

#define TSTEPS 100
#define NB 256
#define INF 2312
#define HIDN 512
#define NOUT 10
#define TC 10          // timesteps per ci chunk
#define NCH 10         // chunks (TC*NCH = TSTEPS)

// ws layout (float offsets)
#define OFF_WT  0                 // 262144 floats (w_rec transposed)
#define OFF_ZB  262144            // 65536 floats = [2][256][512] u8 z-transit
#define OFF_CTR 327680            // 1024 u32: 32 group counters, 128B apart
#define WS_FLOATS 13435904

// build w_recT[j][h] = w_rec[h][j]; zero z-transit + group counters
__global__ __launch_bounds__(256) void init_kernel(float* __restrict__ ws,
                                                   const float* __restrict__ w_rec) {
    int n = blockIdx.x * 256 + threadIdx.x;
    if (n < HIDN * HIDN) {
        int j = n >> 9, h = n & 511;
        ws[n] = w_rec[h * HIDN + j];
    } else if (n < OFF_CTR + 1024) {
        ws[n] = 0.0f;
    }
}

// Stepper-wave barrier (8 waves, LDS monotonic counter)
#define SBAR() do { ++sb_n;                                                     \
    if (lane == 0) __hip_atomic_fetch_add(&sbar, 1u, __ATOMIC_ACQ_REL,          \
                                          __HIP_MEMORY_SCOPE_WORKGROUP);        \
    while (__hip_atomic_load(&sbar, __ATOMIC_ACQUIRE,                           \
                             __HIP_MEMORY_SCOPE_WORKGROUP) < 8u * sb_n)         \
        __builtin_amdgcn_s_sleep(1); } while (0)

// Producer-wave barrier (8 waves)
#define PWBAR() do { ++pw_n;                                                    \
    if (ph == 0) __hip_atomic_fetch_add(&pwbar, 1u, __ATOMIC_ACQ_REL,           \
                                        __HIP_MEMORY_SCOPE_WORKGROUP);          \
    while (__hip_atomic_load(&pwbar, __ATOMIC_ACQUIRE,                          \
                             __HIP_MEMORY_SCOPE_WORKGROUP) < 8u * pw_n)         \
        __builtin_amdgcn_s_sleep(1); } while (0)

// Persistent fused kernel: 256 blocks (= 32 groups x 8 h-chunks) x 1024 thr.
// Waves 0-7 (tid<512): STEPPER — verbatim R9/R10 fused_zf arithmetic; LDS-atomic
//   wave barriers replace __syncthreads; ci read from LDS ring.
// Waves 8-15: PRODUCER — computes this block's ci slice with the FROZEN
//   ascending-k chain acc += (double)x * (double)w (zero-padded tail, R6-proven),
//   10-step chunks into a 2-slot LDS ring. fp64 runs on the DPFP pipe; the
//   stepper's fp32/LDS work hides underneath it.
__global__ __launch_bounds__(1024, 4) void omni(
        const float* __restrict__ X, const float* __restrict__ Win,
        const float* __restrict__ wT, const float* __restrict__ w_out,
        float* __restrict__ out, unsigned char* __restrict__ zb,
        unsigned int* __restrict__ ctr) {
    __shared__ float zf[8 * 512];          // 16 KB  z floats [b][j]
    __shared__ float fbuf[8 * 8 * 64];     // 16 KB  gather partials [w][b][h]
    __shared__ float wout2[2][512];        // 4 KB
    __shared__ float ciR[2][TC][8][64];    // 40 KB  ci ring [slot][tl][b][h]
    __shared__ float Wst[2][64][65];       // 33.3 KB Win K-chunk, dbuf, padded
    __shared__ float Xst[8][TC][64];       // 20 KB  per-wave-private X rows
    __shared__ unsigned int sbar, pbar, cbar, pwbar;

    const int tid = threadIdx.x;
    const int i = (int)blockIdx.x;
    const int c = (i >> 3) & 7;                    // h-chunk / group member
    const int g = (i & 7) | ((i >> 6) << 3);       // group 0..31 (co-XCD)
    const int b0 = g * 8;

    if (tid == 0) { sbar = 0; pbar = 0; cbar = 0; pwbar = 0; }
    {   // stage w_out rows (o=c, o=8+c)
        int r = tid >> 9, j = tid & 511;
        wout2[r][j] = (r == 0) ? w_out[c * HIDN + j]
                               : ((c < 2) ? w_out[(8 + c) * HIDN + j] : 0.0f);
    }
    for (int k = tid; k < 8 * 512; k += 1024) zf[k] = 0.0f;   // z_{-1} = 0
    __syncthreads();   // ONLY uniform barrier; roles diverge below

    unsigned char* zbA = zb + (size_t)b0 * HIDN;
    unsigned char* zbB = zb + 131072 + (size_t)b0 * HIDN;
    unsigned int* myctr = ctr + g * 32;

    if (tid < 512) {
        // ============================ STEPPER ============================
        const int wv = tid >> 6, lane = tid & 63;
        float wreg[64];
#pragma unroll
        for (int qq = 0; qq < 64; ++qq)
            wreg[qq] = wT[(size_t)((wv << 6) + qq) * HIDN + (c << 6) + lane];
        float pos = 0.0f;
        float vA = 0.f, iA = 0.f, vB = 0.f, iB = 0.f;
        unsigned int sb_n = 0;
        int tl = 0, tq = 0;

        for (int t = 0; t < TSTEPS; ++t) {
            if (tl == 0)   // wait for ci chunk tq
                while (__hip_atomic_load(&pbar, __ATOMIC_ACQUIRE,
                        __HIP_MEMORY_SCOPE_WORKGROUP) < 8u * (unsigned)(tq + 1))
                    __builtin_amdgcn_s_sleep(2);

            // ---- gather (frozen fmac chains, verbatim R9) ----
            float f[8] = {0.f, 0.f, 0.f, 0.f, 0.f, 0.f, 0.f, 0.f};
#pragma unroll
            for (int q4 = 0; q4 < 16; ++q4) {
                float4 z4[8];
#pragma unroll
                for (int b = 0; b < 8; ++b)
                    z4[b] = *(const float4*)&zf[b * 512 + (wv << 6) + q4 * 4];
#pragma unroll
                for (int b = 0; b < 8; ++b) {
                    f[b] = __fmaf_rn(z4[b].x, wreg[q4 * 4 + 0], f[b]);
                    f[b] = __fmaf_rn(z4[b].y, wreg[q4 * 4 + 1], f[b]);
                    f[b] = __fmaf_rn(z4[b].z, wreg[q4 * 4 + 2], f[b]);
                    f[b] = __fmaf_rn(z4[b].w, wreg[q4 * 4 + 3], f[b]);
                }
            }
#pragma unroll
            for (int b = 0; b < 8; ++b)
                fbuf[((wv << 3) + b) * 64 + lane] = f[b];
            SBAR();   // partials published; all zf gather-reads done

            // ---- fold + neuron update (frozen) ----
            double acc = 0.0;
#pragma unroll
            for (int c2 = 0; c2 < 8; ++c2)
                acc += (double)fbuf[((c2 << 3) + wv) * 64 + lane];
            float rec32 = (float)acc;
            float civ = ciR[tq & 1][tl][wv][lane];
            float cur = __fadd_rn(__fadd_rn(civ, rec32), 1e-4f);
            float mc = __fmul_rn(2.5e5f, cur);
            pos = __fadd_rn(pos, __fmul_rn(1e-10f, mc));
            bool zbit = __fsub_rn(pos, 2.5e-8f) > 0.0f;
            pos = zbit ? 0.0f : pos;
            unsigned char* zw = (t & 1) ? zbB : zbA;
            zw[wv * HIDN + (c << 6) + lane] = zbit ? 1 : 0;
            __threadfence();   // drain publish before rendezvous
            SBAR();

            // ---- group-local 8-block rendezvous (verbatim R9) ----
            if (tid == 0) {
                __hip_atomic_fetch_add(myctr, 1u, __ATOMIC_ACQ_REL,
                                       __HIP_MEMORY_SCOPE_AGENT);
                const unsigned int tgt = 8u * (unsigned)(t + 1);
                while (__hip_atomic_load(myctr, __ATOMIC_ACQUIRE,
                                         __HIP_MEMORY_SCOPE_AGENT) < tgt)
                    __builtin_amdgcn_s_sleep(2);
            }
            SBAR();
            if (tl == TC - 1 && lane == 0)   // chunk consumed -> ring reusable
                __hip_atomic_fetch_add(&cbar, 1u, __ATOMIC_ACQ_REL,
                                       __HIP_MEMORY_SCOPE_WORKGROUP);

            // ---- pull z_t (u8 -> float) into zf (verbatim R9) ----
            {
                const int bb = wv, j8 = lane * 8;
                uint2 ld = *(const uint2*)(zw + bb * HIDN + j8);
                float4 o0, o1;
                o0.x = (float)(ld.x & 255u);         o0.y = (float)((ld.x >> 8) & 255u);
                o0.z = (float)((ld.x >> 16) & 255u); o0.w = (float)(ld.x >> 24);
                o1.x = (float)(ld.y & 255u);         o1.y = (float)((ld.y >> 8) & 255u);
                o1.z = (float)((ld.y >> 16) & 255u); o1.w = (float)(ld.y >> 24);
                *(float4*)&zf[bb * 512 + j8] = o0;
                *(float4*)&zf[bb * 512 + j8 + 4] = o1;
            }
            SBAR();   // zf ready for LI + next gather

            // ---- LI readout (frozen chain, verbatim R9) ----
#pragma unroll
            for (int oo = 0; oo < 2; ++oo) {
                int o = (oo == 0) ? c : (c < 2 ? 8 + c : -1);
                if (o < 0) continue;
                double part = 0.0;
#pragma unroll
                for (int c2 = 0; c2 < 8; ++c2) {
                    double zfv = (double)zf[wv * 512 + (c2 << 6) + lane];
                    part = __fma_rn(zfv, (double)wout2[oo][(c2 << 6) + lane], part);
                }
#pragma unroll
                for (int off = 32; off > 0; off >>= 1) part += __shfl_down(part, off);
                if (lane == 0) {
                    float inp = (float)part;
                    float vvv = (oo == 0) ? vA : vB;
                    float iiv = (oo == 0) ? iA : iB;
                    float vn = __fadd_rn(vvv, __fmul_rn(1e-8f, __fsub_rn(iiv, vvv)));
                    float t2 = __fmul_rn(2e-8f, iiv);
                    float in2 = __fadd_rn(__fsub_rn(iiv, t2), inp);
                    if (oo == 0) { vA = vn; iA = in2; } else { vB = vn; iB = in2; }
                    out[((size_t)t * NB + (b0 + wv)) * NOUT + o] = vn;
                }
            }
            ++tl; if (tl == TC) { tl = 0; ++tq; }
        }
    } else {
        // ============================ PRODUCER ============================
        const int tid2 = tid - 512;
        const int pb = tid2 >> 6, ph = tid2 & 63;      // wave = batch, lane = h
        const int wj = tid2 >> 3, wq = (tid2 & 7) * 8; // Wst staging role
        const float* wsrc = Win + (size_t)(c * 64 + wj) * INF;
        unsigned int pw_n = 0;

        for (int q = 0; q < NCH; ++q) {
            if (q >= 2)   // ring slot reuse guard
                while (__hip_atomic_load(&cbar, __ATOMIC_ACQUIRE,
                        __HIP_MEMORY_SCOPE_WORKGROUP) < 8u * (unsigned)(q - 1))
                    __builtin_amdgcn_s_sleep(2);
            double acc[TC] = {};
            // prologue: stage Wst buf0 (k0 = 0, fully in-bounds)
#pragma unroll
            for (int u = 0; u < 8; ++u)
                Wst[0][wj][wq + u] = wsrc[wq + u];
            PWBAR();
            for (int ki = 0; ki < 37; ++ki) {
                const int k0 = ki * 64;
                if (ki < 36) {   // stage next K-chunk into other buffer
#pragma unroll
                    for (int u = 0; u < 8; ++u) {
                        int gk = k0 + 64 + wq + u;
                        Wst[(ki + 1) & 1][wj][wq + u] = (gk < INF) ? wsrc[gk] : 0.0f;
                    }
                }
                // stage this wave's X rows (wave-private, lockstep -> no barrier)
#pragma unroll
                for (int tl2 = 0; tl2 < TC; ++tl2) {
                    int row = (q * TC + tl2) * NB + b0 + pb;
                    int gk = k0 + ph;
                    Xst[pb][tl2][ph] = (gk < INF) ? X[(size_t)row * INF + gk] : 0.0f;
                }
                const int buf = ki & 1;
#pragma unroll
                for (int k4 = 0; k4 < 16; ++k4) {
                    float4 xv[TC];
#pragma unroll
                    for (int tl2 = 0; tl2 < TC; ++tl2)
                        xv[tl2] = *(const float4*)&Xst[pb][tl2][k4 * 4];
                    double w0 = (double)Wst[buf][ph][k4 * 4 + 0];
#pragma unroll
                    for (int tl2 = 0; tl2 < TC; ++tl2) acc[tl2] += (double)xv[tl2].x * w0;
                    double w1 = (double)Wst[buf][ph][k4 * 4 + 1];
#pragma unroll
                    for (int tl2 = 0; tl2 < TC; ++tl2) acc[tl2] += (double)xv[tl2].y * w1;
                    double w2 = (double)Wst[buf][ph][k4 * 4 + 2];
#pragma unroll
                    for (int tl2 = 0; tl2 < TC; ++tl2) acc[tl2] += (double)xv[tl2].z * w2;
                    double w3 = (double)Wst[buf][ph][k4 * 4 + 3];
#pragma unroll
                    for (int tl2 = 0; tl2 < TC; ++tl2) acc[tl2] += (double)xv[tl2].w * w3;
                }
                PWBAR();   // Wst dbuf rotate guard
            }
#pragma unroll
            for (int tl2 = 0; tl2 < TC; ++tl2)
                ciR[q & 1][tl2][pb][ph] = (float)acc[tl2];
            if (ph == 0)   // release: ciR writes visible to steppers
                __hip_atomic_fetch_add(&pbar, 1u, __ATOMIC_RELEASE,
                                       __HIP_MEMORY_SCOPE_WORKGROUP);
        }
    }
}

extern "C" void kernel_launch(void* const* d_in, const int* in_sizes, int n_in,
                              void* d_out, int out_size, void* d_ws, size_t ws_size,
                              hipStream_t stream) {
    (void)in_sizes; (void)n_in; (void)out_size;
    const float* x     = (const float*)d_in[0];
    const float* w_in  = (const float*)d_in[1];
    const float* w_rec = (const float*)d_in[2];
    const float* w_out = (const float*)d_in[3];
    float* out = (float*)d_out;
    float* ws  = (float*)d_ws;
    if (ws_size < (size_t)WS_FLOATS * 4) return;

    float* wT = ws + OFF_WT;
    unsigned char* zb = (unsigned char*)(ws + OFF_ZB);
    unsigned int* ctr = (unsigned int*)(ws + OFF_CTR);

    hipLaunchKernelGGL(init_kernel, dim3((OFF_CTR + 1024 + 255) / 256), dim3(256),
                       0, stream, ws, w_rec);
    hipLaunchKernelGGL(omni, dim3(NB), dim3(1024), 0, stream,
                       x, w_in, wT, w_out, out, zb, ctr);
}

// Round 12
// 5030.457 us; speedup vs baseline: 16.9955x; 16.9955x over previous
//
#include <hip/hip_runtime.h>
#include <cstdint>
#include <cstddef>

#define TSTEPS 100
#define NB 256
#define INF 2312
#define HIDN 512
#define NOUT 10

// ws layout (float offsets) — verbatim R10
#define OFF_WT  0                 // 262144 floats (w_rec transposed, 1 MB)
#define OFF_ZB  262144            // 65536 floats = [2][256][512] u8 z-transit
#define OFF_CTR 327680            // 1024 u32: 32 group counters, 128B apart
#define OFF_CI  328704            // 13107200 floats (input-projection cache)
#define WS_FLOATS 13435904        // 53.7 MB

typedef double f64x4 __attribute__((ext_vector_type(4)));

// build w_recT[j][h] = w_rec[h][j]; zero z-transit + group counters
__global__ __launch_bounds__(256) void init_kernel(float* __restrict__ ws,
                                                   const float* __restrict__ w_rec) {
    int n = blockIdx.x * 256 + threadIdx.x;
    if (n < HIDN * HIDN) {
        int j = n >> 9, h = n & 511;
        ws[n] = w_rec[h * HIDN + j];
    } else if (n < OFF_CI) {
        ws[n] = 0.0f;
    }
}

// Hybrid GEMM: C[r][h] = sum_k X[r][k]*Win[h][k], fp64 accumulate, fp32 store.
// Path A (probe-verified): f64 MFMA 16x16x4 — order differs from the chain by
// ~1e-13 rel, far below fp32 half-ulp -> identical rounded ci except ~2e-6 of
// elements by 1 ulp -> zero spike flips (numpy's own sgemm error is larger).
// Path B (fallback, probe fails): R10 vector body VERBATIM (frozen chain).
// Probe: exact-integer algebra, order-independent -> tests lane mapping only.
__global__ __launch_bounds__(256, 2) void gemm_hyb(const float* __restrict__ X,
                                                   const float* __restrict__ Win,
                                                   float* __restrict__ C) {
    __shared__ double As[32][130];   // [k][row], padded (verbatim R10)
    __shared__ double Bs[32][144];   // [k][swz(col)], padded (verbatim R10)
    __shared__ int okls;
    const int tid = threadIdx.x;
    const int lane = tid & 63, l16 = lane & 15, kq = lane >> 4;
    const int wv = tid >> 6;
    const int tx = tid & 15, ty = tid >> 4;          // vector-path roles
    const int row0 = blockIdx.y * 128, col0 = blockIdx.x * 128;
    const int sr = tid >> 1, sk = (tid & 1) * 16;    // staging roles
    const int srz = sr + (sr >> 3);

    // ---- MFMA mapping probe (exact integers; order-independent) ----
    if (tid == 0) okls = 1;
    __syncthreads();
    {
        double md = (double)l16, kd = (double)kq;
        double pa1 = 1.0 + 2.0 * md + 3.0 * kd;      // A1[m=l16][k=kq]
        double pb1 = 2.0 + 5.0 * kd + 7.0 * md;      // B1[k=kq][n=l16]
        double pa2 = 0.5 + md - 2.0 * kd;            // A2
        double pb2 = -3.0 + 2.0 * kd + md;           // B2
        f64x4 pacc;
#pragma unroll
        for (int i = 0; i < 4; ++i)
            pacc[i] = 1000.0 * (double)(4 * kq + i) + (double)l16;  // C0[m][n]
        pacc = __builtin_amdgcn_mfma_f64_16x16x4f64(pa1, pb1, pacc, 0, 0, 0);
        pacc = __builtin_amdgcn_mfma_f64_16x16x4f64(pa2, pb2, pacc, 0, 0, 0);
        bool ok = true;
#pragma unroll
        for (int i = 0; i < 4; ++i) {
            double m = (double)(4 * kq + i), n = (double)l16;
            double e = 1000.0 * m + n;
#pragma unroll
            for (int k = 0; k < 4; ++k) {
                double kk = (double)k;
                e += (1.0 + 2.0 * m + 3.0 * kk) * (2.0 + 5.0 * kk + 7.0 * n);
                e += (0.5 + m - 2.0 * kk) * (-3.0 + 2.0 * kk + n);
            }
            ok = ok && (pacc[i] == e);
        }
        if (!ok) atomicAnd(&okls, 0);
    }
    __syncthreads();
    const bool use_mfma = (okls != 0);

    // ---- staging prologue (verbatim R10) ----
    float4 va[4], vb[4];
#pragma unroll
    for (int q = 0; q < 4; ++q) {
        int gk = sk + q * 4;
        va[q] = *(const float4*)(X + (size_t)(row0 + sr) * INF + gk);
        vb[q] = *(const float4*)(Win + (size_t)(col0 + sr) * INF + gk);
    }
    f64x4 acc[16] = {};   // MFMA: [mt*8+nt]; vector: element (i,j) -> [(i*8+j)>>2][(i*8+j)&3]

    for (int k0 = 0; k0 < INF; k0 += 32) {
        __syncthreads();
#pragma unroll
        for (int q = 0; q < 4; ++q) {
            int kc = sk + q * 4;
            As[kc + 0][sr] = (double)va[q].x; As[kc + 1][sr] = (double)va[q].y;
            As[kc + 2][sr] = (double)va[q].z; As[kc + 3][sr] = (double)va[q].w;
            Bs[kc + 0][srz] = (double)vb[q].x; Bs[kc + 1][srz] = (double)vb[q].y;
            Bs[kc + 2][srz] = (double)vb[q].z; Bs[kc + 3][srz] = (double)vb[q].w;
        }
        __syncthreads();
        const int kn = k0 + 32;
        if (kn < INF) {
#pragma unroll
            for (int q = 0; q < 4; ++q) {
                int gk = kn + sk + q * 4;
                float4 a = make_float4(0.f, 0.f, 0.f, 0.f);
                float4 b = make_float4(0.f, 0.f, 0.f, 0.f);
                if (gk < INF) {   // INF%4==0, gk%4==0 -> full float4 in-bounds
                    a = *(const float4*)(X + (size_t)(row0 + sr) * INF + gk);
                    b = *(const float4*)(Win + (size_t)(col0 + sr) * INF + gk);
                }
                va[q] = a; vb[q] = b;
            }
        }

        if (use_mfma) {
            // rows: wave wv owns wv*32 + {0..31} (2 m-tiles); cols: 8 n-tiles
#pragma unroll
            for (int s = 0; s < 8; ++s) {
                const int ko = s * 4 + kq;           // lane-group kq supplies k=kq
                double a0 = As[ko][wv * 32 + l16];
                double a1 = As[ko][wv * 32 + 16 + l16];
#pragma unroll
                for (int nt = 0; nt < 8; ++nt) {
                    double b = Bs[ko][nt * 18 + l16 + (l16 >> 3)];  // swz(nt*16+l16)
                    acc[nt]     = __builtin_amdgcn_mfma_f64_16x16x4f64(a0, b, acc[nt], 0, 0, 0);
                    acc[8 + nt] = __builtin_amdgcn_mfma_f64_16x16x4f64(a1, b, acc[8 + nt], 0, 0, 0);
                }
            }
        } else {
            // vector fallback (frozen chain, verbatim R10 modulo acc renaming)
#pragma unroll 4
            for (int kk = 0; kk < 32; ++kk) {
                double ad[8], bd[8];
#pragma unroll
                for (int i = 0; i < 8; ++i) ad[i] = As[kk][ty * 8 + i];
#pragma unroll
                for (int j = 0; j < 8; ++j) bd[j] = Bs[kk][9 * tx + j];
#pragma unroll
                for (int i = 0; i < 8; ++i)
#pragma unroll
                    for (int j = 0; j < 8; ++j)
                        acc[(i * 8 + j) >> 2][(i * 8 + j) & 3] += ad[i] * bd[j];
            }
        }
    }

    if (use_mfma) {
#pragma unroll
        for (int mt = 0; mt < 2; ++mt)
#pragma unroll
            for (int nt = 0; nt < 8; ++nt)
#pragma unroll
                for (int i = 0; i < 4; ++i)
                    C[(size_t)(row0 + wv * 32 + mt * 16 + 4 * kq + i) * HIDN
                      + col0 + nt * 16 + l16] = (float)acc[mt * 8 + nt][i];
    } else {
#pragma unroll
        for (int i = 0; i < 8; ++i) {
#pragma unroll
            for (int jj = 0; jj < 2; ++jj) {
                float4 o;
                o.x = (float)acc[(i * 8 + jj * 4 + 0) >> 2][(i * 8 + jj * 4 + 0) & 3];
                o.y = (float)acc[(i * 8 + jj * 4 + 1) >> 2][(i * 8 + jj * 4 + 1) & 3];
                o.z = (float)acc[(i * 8 + jj * 4 + 2) >> 2][(i * 8 + jj * 4 + 2) & 3];
                o.w = (float)acc[(i * 8 + jj * 4 + 3) >> 2][(i * 8 + jj * 4 + 3) & 3];
                *(float4*)(C + (size_t)(row0 + ty * 8 + i) * HIDN + col0 + tx * 8 + jj * 4) = o;
            }
        }
    }
}

// Persistent fused stepper, SALU-free gather. VERBATIM R9/R10 (passed, ~850us).
__global__ __launch_bounds__(512) void fused_zf(const float* __restrict__ ci,
        const float* __restrict__ wT, const float* __restrict__ w_out,
        float* __restrict__ out, unsigned char* __restrict__ zb,
        unsigned int* __restrict__ ctr) {
    __shared__ float zfb[4096];        // 16 KB union: zf[b][j] | fbufT[c2][b][h]
    __shared__ float wout2[2][512];    // 4 KB
    const int tid = threadIdx.x;
    const int wv = tid >> 6, lane = tid & 63;
    const int i = (int)blockIdx.x;
    const int c = (i >> 3) & 7;                    // h-chunk / group member
    const int g = (i & 7) | ((i >> 6) << 3);       // group 0..31 (co-XCD)
    const int b0 = g * 8;

    float wreg[64];
#pragma unroll
    for (int qq = 0; qq < 64; ++qq)
        wreg[qq] = wT[(size_t)((wv << 6) + qq) * HIDN + (c << 6) + lane];

    if (tid < 512) {
        wout2[0][tid] = w_out[c * HIDN + tid];
        wout2[1][tid] = (c < 2) ? w_out[(8 + c) * HIDN + tid] : 0.0f;
    }
    for (int idx = tid; idx < 4096; idx += 512) zfb[idx] = 0.0f;  // z_{-1}=0
    __syncthreads();

    unsigned char* zbA = zb + (size_t)b0 * HIDN;            // [b][j] u8
    unsigned char* zbB = zb + 131072 + (size_t)b0 * HIDN;
    unsigned int* myctr = ctr + g * 32;                     // 128B apart

    float pos = 0.0f;                  // fold phase: thread = (batch wv, h lane)
    float vA = 0.f, iA = 0.f, vB = 0.f, iB = 0.f;   // LI state on lane 0

    for (int t = 0; t < TSTEPS; ++t) {
        float f[8] = {0.f, 0.f, 0.f, 0.f, 0.f, 0.f, 0.f, 0.f};
#pragma unroll
        for (int q4 = 0; q4 < 16; ++q4) {
            float4 z4[8];
#pragma unroll
            for (int b = 0; b < 8; ++b)
                z4[b] = *(const float4*)&zfb[b * 512 + (wv << 6) + q4 * 4];
#pragma unroll
            for (int b = 0; b < 8; ++b) {
                f[b] = __fmaf_rn(z4[b].x, wreg[q4 * 4 + 0], f[b]);
                f[b] = __fmaf_rn(z4[b].y, wreg[q4 * 4 + 1], f[b]);
                f[b] = __fmaf_rn(z4[b].z, wreg[q4 * 4 + 2], f[b]);
                f[b] = __fmaf_rn(z4[b].w, wreg[q4 * 4 + 3], f[b]);
            }
        }
        __syncthreads();   // B1: all zf reads done; region becomes fbufT
#pragma unroll
        for (int b = 0; b < 8; ++b)
            zfb[((wv << 3) + b) * 64 + lane] = f[b];   // fbufT[c2=wv][b][h]
        __syncthreads();   // B2: partials published

        double acc = 0.0;
#pragma unroll
        for (int c2 = 0; c2 < 8; ++c2)
            acc += (double)zfb[((c2 << 3) + wv) * 64 + lane];
        float rec32 = (float)acc;
        float civ = ci[((size_t)t * NB + (b0 + wv)) * HIDN + (c << 6) + lane];
        float cur = __fadd_rn(__fadd_rn(civ, rec32), 1e-4f);   // (in+rec)+I_APP
        float mc = __fmul_rn(2.5e5f, cur);                     // MU*cur
        pos = __fadd_rn(pos, __fmul_rn(1e-10f, mc));           // pos += DT*(..)
        bool zbit = __fsub_rn(pos, 2.5e-8f) > 0.0f;            // pos-W2 > 0
        pos = zbit ? 0.0f : pos;
        unsigned char* zw = (t & 1) ? zbB : zbA;
        zw[wv * HIDN + (c << 6) + lane] = zbit ? 1 : 0;        // publish u8

        __syncthreads();
        if (tid == 0) {
            __hip_atomic_fetch_add(myctr, 1u, __ATOMIC_ACQ_REL,
                                   __HIP_MEMORY_SCOPE_AGENT);
            const unsigned int tgt = 8u * (unsigned)(t + 1);
            while (__hip_atomic_load(myctr, __ATOMIC_ACQUIRE,
                                     __HIP_MEMORY_SCOPE_AGENT) < tgt)
                __builtin_amdgcn_s_sleep(2);
        }
        __syncthreads();   // B3: group's z_t visible (acquire fence on ctr)

        {
            const int bb = tid >> 6, j8 = (tid & 63) * 8;
            uint2 ld = *(const uint2*)(zw + bb * HIDN + j8);
            float4 o0, o1;
            o0.x = (float)(ld.x & 255u);         o0.y = (float)((ld.x >> 8) & 255u);
            o0.z = (float)((ld.x >> 16) & 255u); o0.w = (float)(ld.x >> 24);
            o1.x = (float)(ld.y & 255u);         o1.y = (float)((ld.y >> 8) & 255u);
            o1.z = (float)((ld.y >> 16) & 255u); o1.w = (float)(ld.y >> 24);
            *(float4*)&zfb[bb * 512 + j8] = o0;
            *(float4*)&zfb[bb * 512 + j8 + 4] = o1;
        }
        __syncthreads();   // B4: zf ready for LI + next gather

#pragma unroll
        for (int oo = 0; oo < 2; ++oo) {
            int o = (oo == 0) ? c : (c < 2 ? 8 + c : -1);
            if (o < 0) continue;
            double part = 0.0;
#pragma unroll
            for (int c2 = 0; c2 < 8; ++c2) {
                double zfv = (double)zfb[wv * 512 + (c2 << 6) + lane];
                part = __fma_rn(zfv, (double)wout2[oo][(c2 << 6) + lane], part);
            }
#pragma unroll
            for (int off = 32; off > 0; off >>= 1) part += __shfl_down(part, off);
            if (lane == 0) {
                float inp = (float)part;
                float vvv = (oo == 0) ? vA : vB;
                float iiv = (oo == 0) ? iA : iB;
                float vn = __fadd_rn(vvv, __fmul_rn(1e-8f, __fsub_rn(iiv, vvv)));
                float t2 = __fmul_rn(2e-8f, iiv);
                float in2 = __fadd_rn(__fsub_rn(iiv, t2), inp);
                if (oo == 0) { vA = vn; iA = in2; } else { vB = vn; iB = in2; }
                out[((size_t)t * NB + (b0 + wv)) * NOUT + o] = vn;
            }
        }
    }
}

extern "C" void kernel_launch(void* const* d_in, const int* in_sizes, int n_in,
                              void* d_out, int out_size, void* d_ws, size_t ws_size,
                              hipStream_t stream) {
    (void)in_sizes; (void)n_in; (void)out_size;
    const float* x     = (const float*)d_in[0];
    const float* w_in  = (const float*)d_in[1];
    const float* w_rec = (const float*)d_in[2];
    const float* w_out = (const float*)d_in[3];
    float* out = (float*)d_out;
    float* ws  = (float*)d_ws;
    if (ws_size < (size_t)WS_FLOATS * 4) return;

    float* wT = ws + OFF_WT;
    unsigned char* zb = (unsigned char*)(ws + OFF_ZB);
    unsigned int* ctr = (unsigned int*)(ws + OFF_CTR);
    float* ci = ws + OFF_CI;

    hipLaunchKernelGGL(init_kernel, dim3((OFF_CI + 255) / 256), dim3(256), 0,
                       stream, ws, w_rec);
    hipLaunchKernelGGL(gemm_hyb, dim3(4, 200), dim3(256), 0, stream, x, w_in, ci);
    hipLaunchKernelGGL(fused_zf, dim3(NB), dim3(512), 0, stream,
                       ci, wT, w_out, out, zb, ctr);
}

// Round 13
// 3199.810 us; speedup vs baseline: 26.7188x; 1.5721x over previous
//
#include <hip/hip_runtime.h>
#include <cstdint>
#include <cstddef>

#define TSTEPS 100
#define NB 256
#define INF 2312
#define HIDN 512
#define NOUT 10

// ws layout (float offsets) — verbatim R10/R12
#define OFF_WT  0                 // 262144 floats (w_rec transposed, 1 MB)
#define OFF_ZB  262144            // 65536 floats = [2][256][512] u8 z-transit
#define OFF_CTR 327680            // 1024 u32: 32 group counters, 128B apart
#define OFF_CI  328704            // 13107200 floats (input-projection cache)
#define WS_FLOATS 13435904        // 53.7 MB

typedef double f64x4 __attribute__((ext_vector_type(4)));

// build w_recT[j][h] = w_rec[h][j]; zero z-transit + group counters
__global__ __launch_bounds__(256) void init_kernel(float* __restrict__ ws,
                                                   const float* __restrict__ w_rec) {
    int n = blockIdx.x * 256 + threadIdx.x;
    if (n < HIDN * HIDN) {
        int j = n >> 9, h = n & 511;
        ws[n] = w_rec[h * HIDN + j];
    } else if (n < OFF_CI) {
        ws[n] = 0.0f;
    }
}

// Hybrid GEMM v2: C[r][h] = sum_k X[r][k]*Win[h][k], fp64 accumulate, fp32 store.
// Tile 128x64, 256 threads, f64x4 acc[8] (64 VGPR -> no spill, R12 lesson).
// Probe tests TWO D-layout hypotheses for mfma_f64_16x16x4 (exact-integer,
// order-independent, all lanes/regs, chained C-in):
//   H0: lane l, reg i -> D[m=4*(l>>4)+i][n=l&15]   (failed in R12)
//   H1: lane l, reg i -> D[m=l&15][n=4*(l>>4)+i]   (transposed; R2's symptom)
// MFMA inner loop identical for H0/H1 (only the C-store mapping differs).
// Both fail -> vector fallback with the FROZEN per-element ascending-k chain
// (bit-identical ci to all passing rounds).
__global__ __launch_bounds__(256, 2) void gemm_hyb2(const float* __restrict__ X,
                                                    const float* __restrict__ Win,
                                                    float* __restrict__ C) {
    __shared__ double As[32][131];   // [k][row], padded
    __shared__ double Bs[32][73];    // [k][col], padded
    __shared__ int ok0ls, ok1ls;
    const int tid = threadIdx.x;
    const int lane = tid & 63, l16 = lane & 15, kq = lane >> 4;
    const int wv = tid >> 6;
    const int tx = tid & 15, ty = tid >> 4;          // vector-path roles
    const int row0 = blockIdx.y * 128, col0 = blockIdx.x * 64;
    const int sr = tid >> 1, sk = (tid & 1) * 16;    // A staging
    const int br = tid >> 2, bk = (tid & 3) * 8;     // B staging

    // ---- MFMA layout probe ----
    if (tid == 0) { ok0ls = 1; ok1ls = 1; }
    __syncthreads();
    {
        double md = (double)l16, kd = (double)kq;
        double pa1 = 1.0 + 2.0 * md + 3.0 * kd;      // A1[m=l16][k=kq]
        double pb1 = 2.0 + 5.0 * kd + 7.0 * md;      // B1[k=kq][n=l16]
        double pa2 = 0.5 + md - 2.0 * kd;            // A2
        double pb2 = -3.0 + 2.0 * kd + md;           // B2
        f64x4 pacc;
#pragma unroll
        for (int i = 0; i < 4; ++i)
            pacc[i] = 1000.0 * (double)(4 * kq + i) + (double)l16;   // fed C-in
        pacc = __builtin_amdgcn_mfma_f64_16x16x4f64(pa1, pb1, pacc, 0, 0, 0);
        pacc = __builtin_amdgcn_mfma_f64_16x16x4f64(pa2, pb2, pacc, 0, 0, 0);
        bool ok0 = true, ok1 = true;
#pragma unroll
        for (int i = 0; i < 4; ++i) {
            double fed = 1000.0 * (double)(4 * kq + i) + (double)l16;
            // H0: (m,n) = (4kq+i, l16)
            {
                double m = (double)(4 * kq + i), n = (double)l16, e = fed;
#pragma unroll
                for (int k = 0; k < 4; ++k) {
                    double kk = (double)k;
                    e += (1.0 + 2.0 * m + 3.0 * kk) * (2.0 + 5.0 * kk + 7.0 * n);
                    e += (0.5 + m - 2.0 * kk) * (-3.0 + 2.0 * kk + n);
                }
                ok0 = ok0 && (pacc[i] == e);
            }
            // H1: (m,n) = (l16, 4kq+i)
            {
                double m = (double)l16, n = (double)(4 * kq + i), e = fed;
#pragma unroll
                for (int k = 0; k < 4; ++k) {
                    double kk = (double)k;
                    e += (1.0 + 2.0 * m + 3.0 * kk) * (2.0 + 5.0 * kk + 7.0 * n);
                    e += (0.5 + m - 2.0 * kk) * (-3.0 + 2.0 * kk + n);
                }
                ok1 = ok1 && (pacc[i] == e);
            }
        }
        if (!ok0) atomicAnd(&ok0ls, 0);
        if (!ok1) atomicAnd(&ok1ls, 0);
    }
    __syncthreads();
    const int mode = ok0ls ? 0 : (ok1ls ? 1 : 2);

    // ---- staging prologue (gk <= 28 < INF, always in-bounds) ----
    float4 va[4], vb[2];
#pragma unroll
    for (int q = 0; q < 4; ++q)
        va[q] = *(const float4*)(X + (size_t)(row0 + sr) * INF + sk + q * 4);
#pragma unroll
    for (int q = 0; q < 2; ++q)
        vb[q] = *(const float4*)(Win + (size_t)(col0 + br) * INF + bk + q * 4);

    f64x4 acc[8] = {};   // MFMA: [mt*4+nt]; vector: acc[i] over j=0..3

    for (int k0 = 0; k0 < INF; k0 += 32) {
        __syncthreads();
#pragma unroll
        for (int q = 0; q < 4; ++q) {
            int kc = sk + q * 4;
            As[kc + 0][sr] = (double)va[q].x; As[kc + 1][sr] = (double)va[q].y;
            As[kc + 2][sr] = (double)va[q].z; As[kc + 3][sr] = (double)va[q].w;
        }
#pragma unroll
        for (int q = 0; q < 2; ++q) {
            int kc = bk + q * 4;
            Bs[kc + 0][br] = (double)vb[q].x; Bs[kc + 1][br] = (double)vb[q].y;
            Bs[kc + 2][br] = (double)vb[q].z; Bs[kc + 3][br] = (double)vb[q].w;
        }
        __syncthreads();
        const int kn = k0 + 32;
        if (kn < INF) {
#pragma unroll
            for (int q = 0; q < 4; ++q) {
                int gk = kn + sk + q * 4;
                float4 a = make_float4(0.f, 0.f, 0.f, 0.f);
                if (gk < INF)   // INF%4==0 -> full float4 in-bounds
                    a = *(const float4*)(X + (size_t)(row0 + sr) * INF + gk);
                va[q] = a;
            }
#pragma unroll
            for (int q = 0; q < 2; ++q) {
                int gk = kn + bk + q * 4;
                float4 b = make_float4(0.f, 0.f, 0.f, 0.f);
                if (gk < INF)
                    b = *(const float4*)(Win + (size_t)(col0 + br) * INF + gk);
                vb[q] = b;
            }
        }

        if (mode < 2) {
            // wave wv owns rows wv*32..+31 (2 m-tiles), all 4 n-tiles
#pragma unroll
            for (int s = 0; s < 8; ++s) {
                const int ko = s * 4 + kq;
                double a0 = As[ko][wv * 32 + l16];
                double a1 = As[ko][wv * 32 + 16 + l16];
#pragma unroll
                for (int nt = 0; nt < 4; ++nt) {
                    double b = Bs[ko][nt * 16 + l16];
                    acc[nt]     = __builtin_amdgcn_mfma_f64_16x16x4f64(a0, b, acc[nt], 0, 0, 0);
                    acc[4 + nt] = __builtin_amdgcn_mfma_f64_16x16x4f64(a1, b, acc[4 + nt], 0, 0, 0);
                }
            }
        } else {
            // vector fallback: FROZEN per-element ascending-k chain
#pragma unroll 4
            for (int kk = 0; kk < 32; ++kk) {
                double ad[8], bd[4];
#pragma unroll
                for (int i = 0; i < 8; ++i) ad[i] = As[kk][ty * 8 + i];
#pragma unroll
                for (int j = 0; j < 4; ++j) bd[j] = Bs[kk][tx * 4 + j];
#pragma unroll
                for (int i = 0; i < 8; ++i)
#pragma unroll
                    for (int j = 0; j < 4; ++j)
                        acc[i][j] += ad[i] * bd[j];
            }
        }
    }

    if (mode == 0) {
        // D[m=4kq+i][n=l16]
#pragma unroll
        for (int mt = 0; mt < 2; ++mt)
#pragma unroll
            for (int nt = 0; nt < 4; ++nt)
#pragma unroll
                for (int i = 0; i < 4; ++i)
                    C[(size_t)(row0 + wv * 32 + mt * 16 + 4 * kq + i) * HIDN
                      + col0 + nt * 16 + l16] = (float)acc[mt * 4 + nt][i];
    } else if (mode == 1) {
        // D[m=l16][n=4kq+i] -> float4 stores
#pragma unroll
        for (int mt = 0; mt < 2; ++mt)
#pragma unroll
            for (int nt = 0; nt < 4; ++nt) {
                float4 o;
                o.x = (float)acc[mt * 4 + nt][0]; o.y = (float)acc[mt * 4 + nt][1];
                o.z = (float)acc[mt * 4 + nt][2]; o.w = (float)acc[mt * 4 + nt][3];
                *(float4*)(C + (size_t)(row0 + wv * 32 + mt * 16 + l16) * HIDN
                           + col0 + nt * 16 + 4 * kq) = o;
            }
    } else {
#pragma unroll
        for (int i = 0; i < 8; ++i) {
            float4 o;
            o.x = (float)acc[i][0]; o.y = (float)acc[i][1];
            o.z = (float)acc[i][2]; o.w = (float)acc[i][3];
            *(float4*)(C + (size_t)(row0 + ty * 8 + i) * HIDN + col0 + tx * 4) = o;
        }
    }
}

// Persistent fused stepper, SALU-free gather. VERBATIM R9/R10 (passed, ~850us).
__global__ __launch_bounds__(512) void fused_zf(const float* __restrict__ ci,
        const float* __restrict__ wT, const float* __restrict__ w_out,
        float* __restrict__ out, unsigned char* __restrict__ zb,
        unsigned int* __restrict__ ctr) {
    __shared__ float zfb[4096];        // 16 KB union: zf[b][j] | fbufT[c2][b][h]
    __shared__ float wout2[2][512];    // 4 KB
    const int tid = threadIdx.x;
    const int wv = tid >> 6, lane = tid & 63;
    const int i = (int)blockIdx.x;
    const int c = (i >> 3) & 7;                    // h-chunk / group member
    const int g = (i & 7) | ((i >> 6) << 3);       // group 0..31 (co-XCD)
    const int b0 = g * 8;

    float wreg[64];
#pragma unroll
    for (int qq = 0; qq < 64; ++qq)
        wreg[qq] = wT[(size_t)((wv << 6) + qq) * HIDN + (c << 6) + lane];

    if (tid < 512) {
        wout2[0][tid] = w_out[c * HIDN + tid];
        wout2[1][tid] = (c < 2) ? w_out[(8 + c) * HIDN + tid] : 0.0f;
    }
    for (int idx = tid; idx < 4096; idx += 512) zfb[idx] = 0.0f;  // z_{-1}=0
    __syncthreads();

    unsigned char* zbA = zb + (size_t)b0 * HIDN;            // [b][j] u8
    unsigned char* zbB = zb + 131072 + (size_t)b0 * HIDN;
    unsigned int* myctr = ctr + g * 32;                     // 128B apart

    float pos = 0.0f;                  // fold phase: thread = (batch wv, h lane)
    float vA = 0.f, iA = 0.f, vB = 0.f, iB = 0.f;   // LI state on lane 0

    for (int t = 0; t < TSTEPS; ++t) {
        float f[8] = {0.f, 0.f, 0.f, 0.f, 0.f, 0.f, 0.f, 0.f};
#pragma unroll
        for (int q4 = 0; q4 < 16; ++q4) {
            float4 z4[8];
#pragma unroll
            for (int b = 0; b < 8; ++b)
                z4[b] = *(const float4*)&zfb[b * 512 + (wv << 6) + q4 * 4];
#pragma unroll
            for (int b = 0; b < 8; ++b) {
                f[b] = __fmaf_rn(z4[b].x, wreg[q4 * 4 + 0], f[b]);
                f[b] = __fmaf_rn(z4[b].y, wreg[q4 * 4 + 1], f[b]);
                f[b] = __fmaf_rn(z4[b].z, wreg[q4 * 4 + 2], f[b]);
                f[b] = __fmaf_rn(z4[b].w, wreg[q4 * 4 + 3], f[b]);
            }
        }
        __syncthreads();   // B1: all zf reads done; region becomes fbufT
#pragma unroll
        for (int b = 0; b < 8; ++b)
            zfb[((wv << 3) + b) * 64 + lane] = f[b];   // fbufT[c2=wv][b][h]
        __syncthreads();   // B2: partials published

        double acc = 0.0;
#pragma unroll
        for (int c2 = 0; c2 < 8; ++c2)
            acc += (double)zfb[((c2 << 3) + wv) * 64 + lane];
        float rec32 = (float)acc;
        float civ = ci[((size_t)t * NB + (b0 + wv)) * HIDN + (c << 6) + lane];
        float cur = __fadd_rn(__fadd_rn(civ, rec32), 1e-4f);   // (in+rec)+I_APP
        float mc = __fmul_rn(2.5e5f, cur);                     // MU*cur
        pos = __fadd_rn(pos, __fmul_rn(1e-10f, mc));           // pos += DT*(..)
        bool zbit = __fsub_rn(pos, 2.5e-8f) > 0.0f;            // pos-W2 > 0
        pos = zbit ? 0.0f : pos;
        unsigned char* zw = (t & 1) ? zbB : zbA;
        zw[wv * HIDN + (c << 6) + lane] = zbit ? 1 : 0;        // publish u8

        __syncthreads();
        if (tid == 0) {
            __hip_atomic_fetch_add(myctr, 1u, __ATOMIC_ACQ_REL,
                                   __HIP_MEMORY_SCOPE_AGENT);
            const unsigned int tgt = 8u * (unsigned)(t + 1);
            while (__hip_atomic_load(myctr, __ATOMIC_ACQUIRE,
                                     __HIP_MEMORY_SCOPE_AGENT) < tgt)
                __builtin_amdgcn_s_sleep(2);
        }
        __syncthreads();   // B3: group's z_t visible (acquire fence on ctr)

        {
            const int bb = tid >> 6, j8 = (tid & 63) * 8;
            uint2 ld = *(const uint2*)(zw + bb * HIDN + j8);
            float4 o0, o1;
            o0.x = (float)(ld.x & 255u);         o0.y = (float)((ld.x >> 8) & 255u);
            o0.z = (float)((ld.x >> 16) & 255u); o0.w = (float)(ld.x >> 24);
            o1.x = (float)(ld.y & 255u);         o1.y = (float)((ld.y >> 8) & 255u);
            o1.z = (float)((ld.y >> 16) & 255u); o1.w = (float)(ld.y >> 24);
            *(float4*)&zfb[bb * 512 + j8] = o0;
            *(float4*)&zfb[bb * 512 + j8 + 4] = o1;
        }
        __syncthreads();   // B4: zf ready for LI + next gather

#pragma unroll
        for (int oo = 0; oo < 2; ++oo) {
            int o = (oo == 0) ? c : (c < 2 ? 8 + c : -1);
            if (o < 0) continue;
            double part = 0.0;
#pragma unroll
            for (int c2 = 0; c2 < 8; ++c2) {
                double zfv = (double)zfb[wv * 512 + (c2 << 6) + lane];
                part = __fma_rn(zfv, (double)wout2[oo][(c2 << 6) + lane], part);
            }
#pragma unroll
            for (int off = 32; off > 0; off >>= 1) part += __shfl_down(part, off);
            if (lane == 0) {
                float inp = (float)part;
                float vvv = (oo == 0) ? vA : vB;
                float iiv = (oo == 0) ? iA : iB;
                float vn = __fadd_rn(vvv, __fmul_rn(1e-8f, __fsub_rn(iiv, vvv)));
                float t2 = __fmul_rn(2e-8f, iiv);
                float in2 = __fadd_rn(__fsub_rn(iiv, t2), inp);
                if (oo == 0) { vA = vn; iA = in2; } else { vB = vn; iB = in2; }
                out[((size_t)t * NB + (b0 + wv)) * NOUT + o] = vn;
            }
        }
    }
}

extern "C" void kernel_launch(void* const* d_in, const int* in_sizes, int n_in,
                              void* d_out, int out_size, void* d_ws, size_t ws_size,
                              hipStream_t stream) {
    (void)in_sizes; (void)n_in; (void)out_size;
    const float* x     = (const float*)d_in[0];
    const float* w_in  = (const float*)d_in[1];
    const float* w_rec = (const float*)d_in[2];
    const float* w_out = (const float*)d_in[3];
    float* out = (float*)d_out;
    float* ws  = (float*)d_ws;
    if (ws_size < (size_t)WS_FLOATS * 4) return;

    float* wT = ws + OFF_WT;
    unsigned char* zb = (unsigned char*)(ws + OFF_ZB);
    unsigned int* ctr = (unsigned int*)(ws + OFF_CTR);
    float* ci = ws + OFF_CI;

    hipLaunchKernelGGL(init_kernel, dim3((OFF_CI + 255) / 256), dim3(256), 0,
                       stream, ws, w_rec);
    hipLaunchKernelGGL(gemm_hyb2, dim3(8, 200), dim3(256), 0, stream, x, w_in, ci);
    hipLaunchKernelGGL(fused_zf, dim3(NB), dim3(512), 0, stream,
                       ci, wT, w_out, out, zb, ctr);
}

// Round 14
// 2209.622 us; speedup vs baseline: 38.6922x; 1.4481x over previous
//
#include <hip/hip_runtime.h>
#include <cstdint>
#include <cstddef>

#define TSTEPS 100
#define NB 256
#define INF 2312
#define HIDN 512
#define NOUT 10

// ws layout (float offsets) — verbatim R10; ctr[1023] doubles as MFMA mode slot
#define OFF_WT  0                 // 262144 floats (w_rec transposed, 1 MB)
#define OFF_ZB  262144            // 65536 floats = [2][256][512] u8 z-transit
#define OFF_CTR 327680            // 1024 u32: 32 group counters (stride 32); [1023]=mode
#define OFF_CI  328704            // 13107200 floats (input-projection cache)
#define WS_FLOATS 13435904        // 53.7 MB

typedef double f64x4 __attribute__((ext_vector_type(4)));

// D-layout candidates for mfma_f64_16x16x4: lane l, reg r -> (row m, col n)
__device__ __forceinline__ void dpos_f64(int di, int lane, int r, int& m, int& n) {
    const int l16 = lane & 15, kq = lane >> 4;
    switch (di) {
    case 0:  m = 4 * kq + r;         n = l16;                break;
    case 1:  m = l16;                n = 4 * kq + r;         break;
    case 2:  m = kq + 4 * r;         n = l16;                break;
    case 3:  m = l16;                n = kq + 4 * r;         break;
    case 4:  m = lane >> 2;          n = 4 * (lane & 3) + r; break;
    default: n = lane >> 2;          m = 4 * (lane & 3) + r; break;
    }
}

// build w_recT[j][h] = w_rec[h][j]; zero z-transit + group counters + mode slot
__global__ __launch_bounds__(256) void init_kernel(float* __restrict__ ws,
                                                   const float* __restrict__ w_rec) {
    int n = blockIdx.x * 256 + threadIdx.x;
    if (n < HIDN * HIDN) {
        int j = n >> 9, h = n & 511;
        ws[n] = w_rec[h * HIDN + j];
    } else if (n < OFF_CI) {
        ws[n] = 0.0f;
    }
}

// Exact-integer layout decoder: 2 chained f64 MFMAs, 24 hypothesis checks
// (2 A-feeds x 2 B-feeds x 6 D-maps), 512 exact equality constraints.
// Writes verified mode 0..23, or 255 if none -> vector fallback.
__global__ __launch_bounds__(64) void probe_kernel(unsigned int* __restrict__ mode_out) {
    const int l = threadIdx.x;
    __shared__ unsigned int maskls;
    if (l == 0) maskls = 0xFFFFFFu;
    __syncthreads();
    double a1v = 1.0 + 3.0 * (double)l, b1v = 2.0 + 5.0 * (double)l;
    double a2v = 7.0 - 2.0 * (double)l, b2v = -3.0 + (double)l;
    f64x4 pacc;
#pragma unroll
    for (int r = 0; r < 4; ++r) pacc[r] = 1000.0 * r + 17.0 * l;
    pacc = __builtin_amdgcn_mfma_f64_16x16x4f64(a1v, b1v, pacc, 0, 0, 0);
    pacc = __builtin_amdgcn_mfma_f64_16x16x4f64(a2v, b2v, pacc, 0, 0, 0);
    unsigned int my = 0;
    for (int ai = 0; ai < 2; ++ai)
        for (int bi = 0; bi < 2; ++bi)
            for (int di = 0; di < 6; ++di) {
                bool ok = true;
                for (int r = 0; r < 4; ++r) {
                    int m, n; dpos_f64(di, l, r, m, n);
                    double e = 1000.0 * r + 17.0 * l;
                    for (int k = 0; k < 4; ++k) {
                        int lA = ai ? (4 * m + k) : (m + 16 * k);
                        int lB = bi ? (4 * n + k) : (n + 16 * k);
                        e += (1.0 + 3.0 * (double)lA) * (2.0 + 5.0 * (double)lB)
                           + (7.0 - 2.0 * (double)lA) * (-3.0 + (double)lB);
                    }
                    ok = ok && (pacc[r] == e);
                }
                if (ok) my |= 1u << (ai * 12 + bi * 6 + di);
            }
    atomicAnd(&maskls, my);
    __syncthreads();
    if (l == 0) mode_out[0] = maskls ? (unsigned)(__ffs((int)maskls) - 1) : 255u;
}

// MFMA f64 GEMM (runs only if probe verified a mapping). 64x128 tile, 256 thr,
// wave wv = rows wv*16..+15, acc[8] f64x4 = 64 VGPR (no spill). Feed/store
// addressing configured from the verified mode. fp64 accumulate -> fp32 store:
// reorder error ~1e-15 abs vs fp32 ulp 6e-8 -> spike decisions unchanged.
__global__ __launch_bounds__(256, 2) void gemm_mfma(const float* __restrict__ X,
        const float* __restrict__ Win, float* __restrict__ C,
        const unsigned int* __restrict__ modep) {
    const unsigned int mode = modep[0];
    if (mode >= 24u) return;
    const int di = (int)(mode % 6u), bi = (int)((mode / 6u) & 1u), ai = (int)(mode / 12u);
    __shared__ double As[32][66];    // [k][row], 16.5 KB
    __shared__ double Bs[32][132];   // [k][col], 33 KB
    const int tid = threadIdx.x;
    const int lane = tid & 63, wv = tid >> 6;
    const int a_m = ai ? (lane >> 2) : (lane & 15);
    const int a_k = ai ? (lane & 3) : (lane >> 4);
    const int b_n = bi ? (lane >> 2) : (lane & 15);
    const int b_k = bi ? (lane & 3) : (lane >> 4);
    const int row0 = blockIdx.y * 64, col0 = blockIdx.x * 128;
    const int sra = tid >> 2, ska = (tid & 3) * 8;    // A staging: 8 floats
    const int srb = tid >> 1, skb = (tid & 1) * 16;   // B staging: 16 floats

    float4 va[2], vb[4];
#pragma unroll
    for (int q = 0; q < 2; ++q)
        va[q] = *(const float4*)(X + (size_t)(row0 + sra) * INF + ska + q * 4);
#pragma unroll
    for (int q = 0; q < 4; ++q)
        vb[q] = *(const float4*)(Win + (size_t)(col0 + srb) * INF + skb + q * 4);

    f64x4 acc[8] = {};
    for (int k0 = 0; k0 < INF; k0 += 32) {
        __syncthreads();
#pragma unroll
        for (int q = 0; q < 2; ++q) {
            int kc = ska + q * 4;
            As[kc + 0][sra] = (double)va[q].x; As[kc + 1][sra] = (double)va[q].y;
            As[kc + 2][sra] = (double)va[q].z; As[kc + 3][sra] = (double)va[q].w;
        }
#pragma unroll
        for (int q = 0; q < 4; ++q) {
            int kc = skb + q * 4;
            Bs[kc + 0][srb] = (double)vb[q].x; Bs[kc + 1][srb] = (double)vb[q].y;
            Bs[kc + 2][srb] = (double)vb[q].z; Bs[kc + 3][srb] = (double)vb[q].w;
        }
        __syncthreads();
        const int kn = k0 + 32;
        if (kn < INF) {
#pragma unroll
            for (int q = 0; q < 2; ++q) {
                int gk = kn + ska + q * 4;
                float4 a = make_float4(0.f, 0.f, 0.f, 0.f);
                if (gk < INF)   // INF%4==0 -> full float4 in-bounds
                    a = *(const float4*)(X + (size_t)(row0 + sra) * INF + gk);
                va[q] = a;
            }
#pragma unroll
            for (int q = 0; q < 4; ++q) {
                int gk = kn + skb + q * 4;
                float4 b = make_float4(0.f, 0.f, 0.f, 0.f);
                if (gk < INF)
                    b = *(const float4*)(Win + (size_t)(col0 + srb) * INF + gk);
                vb[q] = b;
            }
        }
#pragma unroll
        for (int s = 0; s < 8; ++s) {
            double a = As[s * 4 + a_k][wv * 16 + a_m];
#pragma unroll
            for (int nt = 0; nt < 8; ++nt) {
                double b = Bs[s * 4 + b_k][nt * 16 + b_n];
                acc[nt] = __builtin_amdgcn_mfma_f64_16x16x4f64(a, b, acc[nt], 0, 0, 0);
            }
        }
    }
#pragma unroll
    for (int nt = 0; nt < 8; ++nt)
#pragma unroll
        for (int r = 0; r < 4; ++r) {
            int m, n; dpos_f64(di, lane, r, m, n);
            C[(size_t)(row0 + wv * 16 + m) * HIDN + col0 + nt * 16 + n]
                = (float)acc[nt][r];
        }
}

// Vector GEMM fallback: VERBATIM R10 gemm_in (frozen per-element ascending-k
// fp64 chain -> bit-identical ci). Runs only if the probe found no mapping.
__global__ __launch_bounds__(256, 2) void gemm_vec(const float* __restrict__ X,
        const float* __restrict__ Win, float* __restrict__ C,
        const unsigned int* __restrict__ modep) {
    if (modep[0] < 24u) return;
    __shared__ double As[32][130];   // [k][row], padded
    __shared__ double Bs[32][144];   // [k][swz(col)], padded
    const int tid = threadIdx.x;
    const int tx = tid & 15;             // cols tx*8..+7
    const int ty = tid >> 4;             // rows ty*8..+7
    const int row0 = blockIdx.y * 128, col0 = blockIdx.x * 128;
    const int sr = tid >> 1, sk = (tid & 1) * 16;   // staging: row/col, k-base
    const int srz = sr + (sr >> 3);      // swizzled B col position
    float4 va[4], vb[4];
#pragma unroll
    for (int q = 0; q < 4; ++q) {
        int gk = sk + q * 4;
        va[q] = *(const float4*)(X + (size_t)(row0 + sr) * INF + gk);
        vb[q] = *(const float4*)(Win + (size_t)(col0 + sr) * INF + gk);
    }
    double acc[8][8] = {};
    for (int k0 = 0; k0 < INF; k0 += 32) {
        __syncthreads();
#pragma unroll
        for (int q = 0; q < 4; ++q) {
            int kc = sk + q * 4;
            As[kc + 0][sr] = (double)va[q].x; As[kc + 1][sr] = (double)va[q].y;
            As[kc + 2][sr] = (double)va[q].z; As[kc + 3][sr] = (double)va[q].w;
            Bs[kc + 0][srz] = (double)vb[q].x; Bs[kc + 1][srz] = (double)vb[q].y;
            Bs[kc + 2][srz] = (double)vb[q].z; Bs[kc + 3][srz] = (double)vb[q].w;
        }
        __syncthreads();
        const int kn = k0 + 32;
        if (kn < INF) {
#pragma unroll
            for (int q = 0; q < 4; ++q) {
                int gk = kn + sk + q * 4;
                float4 a = make_float4(0.f, 0.f, 0.f, 0.f);
                float4 b = make_float4(0.f, 0.f, 0.f, 0.f);
                if (gk < INF) {
                    a = *(const float4*)(X + (size_t)(row0 + sr) * INF + gk);
                    b = *(const float4*)(Win + (size_t)(col0 + sr) * INF + gk);
                }
                va[q] = a; vb[q] = b;
            }
        }
#pragma unroll 4
        for (int kk = 0; kk < 32; ++kk) {
            double ad[8], bd[8];
#pragma unroll
            for (int i = 0; i < 8; ++i) ad[i] = As[kk][ty * 8 + i];
#pragma unroll
            for (int j = 0; j < 8; ++j) bd[j] = Bs[kk][9 * tx + j];  // swz(tx*8+j)
#pragma unroll
            for (int i = 0; i < 8; ++i)
#pragma unroll
                for (int j = 0; j < 8; ++j)
                    acc[i][j] += ad[i] * bd[j];
        }
    }
#pragma unroll
    for (int i = 0; i < 8; ++i) {
#pragma unroll
        for (int jj = 0; jj < 2; ++jj) {
            float4 o;
            o.x = (float)acc[i][jj * 4 + 0]; o.y = (float)acc[i][jj * 4 + 1];
            o.z = (float)acc[i][jj * 4 + 2]; o.w = (float)acc[i][jj * 4 + 3];
            *(float4*)(C + (size_t)(row0 + ty * 8 + i) * HIDN + col0 + tx * 8 + jj * 4) = o;
        }
    }
}

// Persistent fused stepper, SALU-free gather. VERBATIM R9/R10 (passed, ~850us).
__global__ __launch_bounds__(512) void fused_zf(const float* __restrict__ ci,
        const float* __restrict__ wT, const float* __restrict__ w_out,
        float* __restrict__ out, unsigned char* __restrict__ zb,
        unsigned int* __restrict__ ctr) {
    __shared__ float zfb[4096];        // 16 KB union: zf[b][j] | fbufT[c2][b][h]
    __shared__ float wout2[2][512];    // 4 KB
    const int tid = threadIdx.x;
    const int wv = tid >> 6, lane = tid & 63;
    const int i = (int)blockIdx.x;
    const int c = (i >> 3) & 7;                    // h-chunk / group member
    const int g = (i & 7) | ((i >> 6) << 3);       // group 0..31 (co-XCD)
    const int b0 = g * 8;

    float wreg[64];
#pragma unroll
    for (int qq = 0; qq < 64; ++qq)
        wreg[qq] = wT[(size_t)((wv << 6) + qq) * HIDN + (c << 6) + lane];

    if (tid < 512) {
        wout2[0][tid] = w_out[c * HIDN + tid];
        wout2[1][tid] = (c < 2) ? w_out[(8 + c) * HIDN + tid] : 0.0f;
    }
    for (int idx = tid; idx < 4096; idx += 512) zfb[idx] = 0.0f;  // z_{-1}=0
    __syncthreads();

    unsigned char* zbA = zb + (size_t)b0 * HIDN;            // [b][j] u8
    unsigned char* zbB = zb + 131072 + (size_t)b0 * HIDN;
    unsigned int* myctr = ctr + g * 32;                     // 128B apart

    float pos = 0.0f;                  // fold phase: thread = (batch wv, h lane)
    float vA = 0.f, iA = 0.f, vB = 0.f, iB = 0.f;   // LI state on lane 0

    for (int t = 0; t < TSTEPS; ++t) {
        float f[8] = {0.f, 0.f, 0.f, 0.f, 0.f, 0.f, 0.f, 0.f};
#pragma unroll
        for (int q4 = 0; q4 < 16; ++q4) {
            float4 z4[8];
#pragma unroll
            for (int b = 0; b < 8; ++b)
                z4[b] = *(const float4*)&zfb[b * 512 + (wv << 6) + q4 * 4];
#pragma unroll
            for (int b = 0; b < 8; ++b) {
                f[b] = __fmaf_rn(z4[b].x, wreg[q4 * 4 + 0], f[b]);
                f[b] = __fmaf_rn(z4[b].y, wreg[q4 * 4 + 1], f[b]);
                f[b] = __fmaf_rn(z4[b].z, wreg[q4 * 4 + 2], f[b]);
                f[b] = __fmaf_rn(z4[b].w, wreg[q4 * 4 + 3], f[b]);
            }
        }
        __syncthreads();   // B1: all zf reads done; region becomes fbufT
#pragma unroll
        for (int b = 0; b < 8; ++b)
            zfb[((wv << 3) + b) * 64 + lane] = f[b];   // fbufT[c2=wv][b][h]
        __syncthreads();   // B2: partials published

        double acc = 0.0;
#pragma unroll
        for (int c2 = 0; c2 < 8; ++c2)
            acc += (double)zfb[((c2 << 3) + wv) * 64 + lane];
        float rec32 = (float)acc;
        float civ = ci[((size_t)t * NB + (b0 + wv)) * HIDN + (c << 6) + lane];
        float cur = __fadd_rn(__fadd_rn(civ, rec32), 1e-4f);   // (in+rec)+I_APP
        float mc = __fmul_rn(2.5e5f, cur);                     // MU*cur
        pos = __fadd_rn(pos, __fmul_rn(1e-10f, mc));           // pos += DT*(..)
        bool zbit = __fsub_rn(pos, 2.5e-8f) > 0.0f;            // pos-W2 > 0
        pos = zbit ? 0.0f : pos;
        unsigned char* zw = (t & 1) ? zbB : zbA;
        zw[wv * HIDN + (c << 6) + lane] = zbit ? 1 : 0;        // publish u8

        __syncthreads();
        if (tid == 0) {
            __hip_atomic_fetch_add(myctr, 1u, __ATOMIC_ACQ_REL,
                                   __HIP_MEMORY_SCOPE_AGENT);
            const unsigned int tgt = 8u * (unsigned)(t + 1);
            while (__hip_atomic_load(myctr, __ATOMIC_ACQUIRE,
                                     __HIP_MEMORY_SCOPE_AGENT) < tgt)
                __builtin_amdgcn_s_sleep(2);
        }
        __syncthreads();   // B3: group's z_t visible (acquire fence on ctr)

        {
            const int bb = tid >> 6, j8 = (tid & 63) * 8;
            uint2 ld = *(const uint2*)(zw + bb * HIDN + j8);
            float4 o0, o1;
            o0.x = (float)(ld.x & 255u);         o0.y = (float)((ld.x >> 8) & 255u);
            o0.z = (float)((ld.x >> 16) & 255u); o0.w = (float)(ld.x >> 24);
            o1.x = (float)(ld.y & 255u);         o1.y = (float)((ld.y >> 8) & 255u);
            o1.z = (float)((ld.y >> 16) & 255u); o1.w = (float)(ld.y >> 24);
            *(float4*)&zfb[bb * 512 + j8] = o0;
            *(float4*)&zfb[bb * 512 + j8 + 4] = o1;
        }
        __syncthreads();   // B4: zf ready for LI + next gather

#pragma unroll
        for (int oo = 0; oo < 2; ++oo) {
            int o = (oo == 0) ? c : (c < 2 ? 8 + c : -1);
            if (o < 0) continue;
            double part = 0.0;
#pragma unroll
            for (int c2 = 0; c2 < 8; ++c2) {
                double zfv = (double)zfb[wv * 512 + (c2 << 6) + lane];
                part = __fma_rn(zfv, (double)wout2[oo][(c2 << 6) + lane], part);
            }
#pragma unroll
            for (int off = 32; off > 0; off >>= 1) part += __shfl_down(part, off);
            if (lane == 0) {
                float inp = (float)part;
                float vvv = (oo == 0) ? vA : vB;
                float iiv = (oo == 0) ? iA : iB;
                float vn = __fadd_rn(vvv, __fmul_rn(1e-8f, __fsub_rn(iiv, vvv)));
                float t2 = __fmul_rn(2e-8f, iiv);
                float in2 = __fadd_rn(__fsub_rn(iiv, t2), inp);
                if (oo == 0) { vA = vn; iA = in2; } else { vB = vn; iB = in2; }
                out[((size_t)t * NB + (b0 + wv)) * NOUT + o] = vn;
            }
        }
    }
}

extern "C" void kernel_launch(void* const* d_in, const int* in_sizes, int n_in,
                              void* d_out, int out_size, void* d_ws, size_t ws_size,
                              hipStream_t stream) {
    (void)in_sizes; (void)n_in; (void)out_size;
    const float* x     = (const float*)d_in[0];
    const float* w_in  = (const float*)d_in[1];
    const float* w_rec = (const float*)d_in[2];
    const float* w_out = (const float*)d_in[3];
    float* out = (float*)d_out;
    float* ws  = (float*)d_ws;
    if (ws_size < (size_t)WS_FLOATS * 4) return;

    float* wT = ws + OFF_WT;
    unsigned char* zb = (unsigned char*)(ws + OFF_ZB);
    unsigned int* ctr = (unsigned int*)(ws + OFF_CTR);
    unsigned int* mode = ctr + 1023;   // unused counter slot (g*32 <= 992)
    float* ci = ws + OFF_CI;

    hipLaunchKernelGGL(init_kernel, dim3((OFF_CI + 255) / 256), dim3(256), 0,
                       stream, ws, w_rec);
    hipLaunchKernelGGL(probe_kernel, dim3(1), dim3(64), 0, stream, mode);
    hipLaunchKernelGGL(gemm_mfma, dim3(4, 400), dim3(256), 0, stream,
                       x, w_in, ci, mode);
    hipLaunchKernelGGL(gemm_vec, dim3(4, 200), dim3(256), 0, stream,
                       x, w_in, ci, mode);
    hipLaunchKernelGGL(fused_zf, dim3(NB), dim3(512), 0, stream,
                       ci, wT, w_out, out, zb, ctr);
}